// Round 5
// baseline (943.432 us; speedup 1.0000x reference)
//
#include <hip/hip_runtime.h>
#include <math.h>

#define NNODES 100000
#define NEDGES 1600000
#define DF 128
#define ED 16
#define NBLK_SCAN ((NNODES + 255) / 256)   // 391

typedef float v2f __attribute__((ext_vector_type(2)));

// ---------------- prep: interleave layer1/layer2 edge-MLP params for packed math
// wint[j*32 + 2k + L] = wL[k*128 + j]   (j in [0,128), k in [0,16), L in {0,1})
// bw2[2j + L] = bL[j] ;  bw2[256 + 2j + L] = w2L[j]
__global__ void k_prep(const float* __restrict__ m1w1, const float* __restrict__ m2w1,
                       const float* __restrict__ m1b1, const float* __restrict__ m2b1,
                       const float* __restrict__ m1w2, const float* __restrict__ m2w2,
                       float* __restrict__ wint, float* __restrict__ bw2) {
    int t = blockIdx.x * blockDim.x + threadIdx.x;
    if (t < 4096) {
        int j = t >> 5, r = t & 31;
        int k = r >> 1, L = r & 1;
        const float* src = L ? m2w1 : m1w1;
        wint[t] = src[k * DF + j];
    } else if (t < 4096 + 256) {
        int i = t - 4096;
        int j = i >> 1, L = i & 1;
        bw2[i] = L ? m2b1[j] : m1b1[j];
    } else if (t < 4096 + 512) {
        int i = t - 4096 - 256;
        int j = i >> 1, L = i & 1;
        bw2[256 + i] = L ? m2w2[j] : m1w2[j];
    }
}

// ---------------- deg init (self-loop weight 1) + zero in-degree counters
__global__ void k_deg_init(float* __restrict__ d1, float* __restrict__ d2,
                           int* __restrict__ cnt) {
    int i = blockIdx.x * blockDim.x + threadIdx.x;
    if (i < NNODES) { d1[i] = 1.f; d2[i] = 1.f; cnt[i] = 0; }
}

// ---------------- edge gates, packed layer-pair math, 2 edges/thread,
// weights fetched via wave-uniform (scalar-path) global loads. No LDS.
__global__ __launch_bounds__(256) void k_gates4(
    const float* __restrict__ ea, const int* __restrict__ ei,
    const float* __restrict__ wint, const float* __restrict__ bw2,
    const float* __restrict__ b21, const float* __restrict__ b22,
    float* __restrict__ g1, float* __restrict__ g2,
    float* __restrict__ deg1, float* __restrict__ deg2,
    int* __restrict__ cnt) {
    int t = threadIdx.x;
    size_t e0 = (size_t)blockIdx.x * 512 + t;   // this thread: e0 and e0+256

    float a0[16], a1[16];
    const float4* p0 = (const float4*)(ea + e0 * ED);
    const float4* p1 = (const float4*)(ea + (e0 + 256) * ED);
#pragma unroll
    for (int q = 0; q < 4; q++) {
        float4 v = p0[q];
        a0[q*4+0] = v.x; a0[q*4+1] = v.y; a0[q*4+2] = v.z; a0[q*4+3] = v.w;
        float4 u = p1[q];
        a1[q*4+0] = u.x; a1[q*4+1] = u.y; a1[q*4+2] = u.z; a1[q*4+3] = u.w;
    }

    const v2f* wv = (const v2f*)wint;
    const v2f* bv = (const v2f*)bw2;
    const v2f* sv = (const v2f*)(bw2 + 256);

    v2f z0, z1;
    z0.x = b21[0]; z0.y = b22[0];
    z1 = z0;
#pragma unroll 2
    for (int j = 0; j < 128; j++) {
        const v2f* wp = wv + j * 16;
        v2f h0 = bv[j], h1 = h0;
#pragma unroll
        for (int k = 0; k < 16; k++) {
            v2f w = wp[k];          // wave-uniform -> s_load
            h0 += w * a0[k];        // v_pk_fma_f32
            h1 += w * a1[k];
        }
        v2f s = sv[j];
        z0 += __builtin_elementwise_max(h0, (v2f)(0.f)) * s;
        z1 += __builtin_elementwise_max(h1, (v2f)(0.f)) * s;
    }

#pragma unroll
    for (int half = 0; half < 2; half++) {
        v2f z = half ? z1 : z0;
        size_t e = e0 + (half ? 256 : 0);
        float ga = 1.f / (1.f + expf(-z.x));
        float gb = 1.f / (1.f + expf(-z.y));
        g1[e] = ga; g2[e] = gb;
        int c = ei[NEDGES + e];
        atomicAdd(&deg1[c], ga);
        atomicAdd(&deg2[c], gb);
        atomicAdd(&cnt[c], 1);
    }
}

// ---------------- deg -> rsqrt(deg) in place (deg >= 1 always)
__global__ void k_rsqrt(float* __restrict__ d1, float* __restrict__ d2) {
    int i = blockIdx.x * blockDim.x + threadIdx.x;
    if (i < NNODES) { d1[i] = rsqrtf(d1[i]); d2[i] = rsqrtf(d2[i]); }
}

// ---------------- scan phase 1: per-256-block exclusive scan + block sums
__global__ __launch_bounds__(256) void k_scan1(const int* __restrict__ cnt,
                                               int* __restrict__ offs,
                                               int* __restrict__ partial) {
    __shared__ int s[256];
    int t = threadIdx.x;
    int gid = blockIdx.x * 256 + t;
    int own = (gid < NNODES) ? cnt[gid] : 0;
    s[t] = own;
    __syncthreads();
    for (int off = 1; off < 256; off <<= 1) {
        int v = (t >= off) ? s[t - off] : 0;
        __syncthreads();
        s[t] += v;
        __syncthreads();
    }
    if (gid < NNODES) offs[gid] = s[t] - own;   // exclusive
    if (t == 255) partial[blockIdx.x] = s[255];
}

// ---------------- scan phase 2: single block scans the block sums (exclusive)
__global__ __launch_bounds__(512) void k_scan2(int* __restrict__ partial) {
    __shared__ int s[512];
    int t = threadIdx.x;
    int own = (t < NBLK_SCAN) ? partial[t] : 0;
    s[t] = own;
    __syncthreads();
    for (int off = 1; off < 512; off <<= 1) {
        int v = (t >= off) ? s[t - off] : 0;
        __syncthreads();
        s[t] += v;
        __syncthreads();
    }
    if (t < NBLK_SCAN) partial[t] = s[t] - own;  // exclusive
}

// ---------------- scan phase 3: add block offsets; init cursor; offs[N]=E
__global__ void k_scan3(int* __restrict__ offs, const int* __restrict__ partial,
                        int* __restrict__ cur) {
    int gid = blockIdx.x * blockDim.x + threadIdx.x;
    if (gid < NNODES) {
        int v = offs[gid] + partial[gid >> 8];
        offs[gid] = v;
        cur[gid] = v;
    }
    if (gid == 0) offs[NNODES] = NEDGES;
}

// ---------------- scatter edges into CSR slots + precompute per-layer norms
__global__ __launch_bounds__(256) void k_scatter(
    const int* __restrict__ ei, const float* __restrict__ g1,
    const float* __restrict__ g2, const float* __restrict__ dinv1,
    const float* __restrict__ dinv2, int* __restrict__ cur,
    int* __restrict__ prow, float* __restrict__ wl1, float* __restrict__ wl2) {
    int e = blockIdx.x * 256 + threadIdx.x;
    if (e >= NEDGES) return;
    int r = ei[e], c = ei[NEDGES + e];
    int pos = atomicAdd(&cur[c], 1);
    prow[pos] = r;
    wl1[pos] = dinv1[r] * g1[e] * dinv1[c];
    wl2[pos] = dinv2[r] * g2[e] * dinv2[c];
}

// ---------------- fp32 GEMM: Y[M,128] = act(X)[M,128] @ W[128,128]
template <int RELU>
__global__ __launch_bounds__(256) void k_gemm(const float* __restrict__ X,
                                              const float* __restrict__ W,
                                              float* __restrict__ Y, int M) {
    __shared__ __align__(16) float sX[64 * 68];
    __shared__ __align__(16) float sW[64 * 132];
    int t = threadIdx.x;
    int row0 = blockIdx.x * 64;
    int tx = t & 15, ty = t >> 4;

    float acc[4][8];
#pragma unroll
    for (int i = 0; i < 4; i++)
#pragma unroll
        for (int j = 0; j < 8; j++) acc[i][j] = 0.f;

    for (int kt = 0; kt < 128; kt += 64) {
        for (int i = t; i < 1024; i += 256) {
            int r = i >> 4, c4 = i & 15;
            float4 v = make_float4(0.f, 0.f, 0.f, 0.f);
            if (row0 + r < M) v = ((const float4*)X)[(size_t)(row0 + r) * 32 + (kt >> 2) + c4];
            if (RELU) {
                v.x = fmaxf(v.x, 0.f); v.y = fmaxf(v.y, 0.f);
                v.z = fmaxf(v.z, 0.f); v.w = fmaxf(v.w, 0.f);
            }
            ((float4*)(sX + r * 68))[c4] = v;
        }
        for (int i = t; i < 2048; i += 256) {
            int r = i >> 5, c4 = i & 31;
            float4 v = ((const float4*)W)[(size_t)(kt + r) * 32 + c4];
            ((float4*)(sW + r * 132))[c4] = v;
        }
        __syncthreads();
#pragma unroll 8
        for (int k = 0; k < 64; k++) {
            float xv[4];
#pragma unroll
            for (int i = 0; i < 4; i++) xv[i] = sX[(ty * 4 + i) * 68 + k];
            float4 wA = *(const float4*)(sW + k * 132 + tx * 4);
            float4 wB = *(const float4*)(sW + k * 132 + 64 + tx * 4);
#pragma unroll
            for (int i = 0; i < 4; i++) {
                acc[i][0] += xv[i] * wA.x; acc[i][1] += xv[i] * wA.y;
                acc[i][2] += xv[i] * wA.z; acc[i][3] += xv[i] * wA.w;
                acc[i][4] += xv[i] * wB.x; acc[i][5] += xv[i] * wB.y;
                acc[i][6] += xv[i] * wB.z; acc[i][7] += xv[i] * wB.w;
            }
        }
        __syncthreads();
    }
#pragma unroll
    for (int i = 0; i < 4; i++) {
        int r = row0 + ty * 4 + i;
        if (r < M) {
            float4 o1 = make_float4(acc[i][0], acc[i][1], acc[i][2], acc[i][3]);
            float4 o2 = make_float4(acc[i][4], acc[i][5], acc[i][6], acc[i][7]);
            *(float4*)(Y + (size_t)r * 128 + tx * 4) = o1;
            *(float4*)(Y + (size_t)r * 128 + 64 + tx * 4) = o2;
        }
    }
}

// ---------------- CSR aggregation: one wave per node, register accumulation.
__global__ __launch_bounds__(256) void k_aggcsr(
    const int* __restrict__ offs, const int* __restrict__ prow,
    const float* __restrict__ wl, const float* __restrict__ dinv,
    const float* __restrict__ h, float* __restrict__ out) {
    int node = blockIdx.x * 4 + (threadIdx.x >> 6);
    if (node >= NNODES) return;
    int lane = threadIdx.x & 63;
    int beg = offs[node], end = offs[node + 1];
    float d = dinv[node];
    float2 hv = ((const float2*)h)[(size_t)node * 64 + lane];
    float2 acc;
    acc.x = d * d * hv.x;
    acc.y = d * d * hv.y;
    int   r_n = 0; float w_n = 0.f;
    if (beg < end) { r_n = prow[beg]; w_n = wl[beg]; }
    for (int e = beg; e < end; e++) {
        int   r = r_n;
        float w = w_n;
        if (e + 1 < end) { r_n = prow[e + 1]; w_n = wl[e + 1]; }
        float2 v = ((const float2*)h)[(size_t)r * 64 + lane];
        acc.x += w * v.x;
        acc.y += w * v.y;
    }
    ((float2*)out)[(size_t)node * 64 + lane] = acc;
}

extern "C" void kernel_launch(void* const* d_in, const int* in_sizes, int n_in,
                              void* d_out, int out_size, void* d_ws, size_t ws_size,
                              hipStream_t stream) {
    const float* x    = (const float*)d_in[0];
    const int*   ei   = (const int*)d_in[1];
    const float* ea   = (const float*)d_in[2];
    const float* W1   = (const float*)d_in[3];
    const float* m1w1 = (const float*)d_in[4];
    const float* m1b1 = (const float*)d_in[5];
    const float* m1w2 = (const float*)d_in[6];
    const float* m1b2 = (const float*)d_in[7];
    const float* W2   = (const float*)d_in[8];
    const float* m2w1 = (const float*)d_in[9];
    const float* m2b1 = (const float*)d_in[10];
    const float* m2w2 = (const float*)d_in[11];
    const float* m2b2 = (const float*)d_in[12];
    float* out = (float*)d_out;

    float* ws    = (float*)d_ws;
    float* g1    = ws;                               // E
    float* g2    = g1 + NEDGES;                      // E
    float* deg1  = g2 + NEDGES;                      // N
    float* deg2  = deg1 + NNODES;                    // N
    float* hbuf  = deg2 + NNODES;                    // N*128
    float* aggbf = hbuf + (size_t)NNODES * 128;      // N*128
    float* wint  = aggbf + (size_t)NNODES * 128;     // 4096
    float* bw2   = wint + 4096;                      // 512
    float* wl1   = bw2 + 512;                        // E
    float* wl2   = wl1 + NEDGES;                     // E
    int*   cnt   = (int*)(wl2 + NEDGES);             // N (also cursor)
    int*   offs  = cnt + NNODES;                     // N+1
    int*   part  = offs + NNODES + 1;                // 1024
    int*   prow  = part + 1024;                      // E

    k_prep<<<18, 256, 0, stream>>>(m1w1, m2w1, m1b1, m2b1, m1w2, m2w2, wint, bw2);
    k_deg_init<<<(NNODES + 255) / 256, 256, 0, stream>>>(deg1, deg2, cnt);
    k_gates4<<<NEDGES / 512, 256, 0, stream>>>(ea, ei, wint, bw2, m1b2, m2b2,
                                               g1, g2, deg1, deg2, cnt);
    k_rsqrt<<<(NNODES + 255) / 256, 256, 0, stream>>>(deg1, deg2);

    // CSR build (graph shared by both layers)
    k_scan1<<<NBLK_SCAN, 256, 0, stream>>>(cnt, offs, part);
    k_scan2<<<1, 512, 0, stream>>>(part);
    k_scan3<<<(NNODES + 255) / 256, 256, 0, stream>>>(offs, part, cnt);
    k_scatter<<<NEDGES / 256, 256, 0, stream>>>(ei, g1, g2, deg1, deg2,
                                                cnt, prow, wl1, wl2);

    // layer 1
    k_gemm<0><<<(NNODES + 63) / 64, 256, 0, stream>>>(x, W1, hbuf, NNODES);
    k_aggcsr<<<(NNODES + 3) / 4, 256, 0, stream>>>(offs, prow, wl1, deg1, hbuf, aggbf);

    // layer 2 (relu fused into GEMM load)
    k_gemm<1><<<(NNODES + 63) / 64, 256, 0, stream>>>(aggbf, W2, hbuf, NNODES);
    k_aggcsr<<<(NNODES + 3) / 4, 256, 0, stream>>>(offs, prow, wl2, deg2, hbuf, out);
}